// Round 3
// baseline (310.786 us; speedup 1.0000x reference)
//
#include <hip/hip_runtime.h>
#include <stdint.h>

typedef _Float16 h8v __attribute__((ext_vector_type(8)));
typedef _Float16 h4v __attribute__((ext_vector_type(4)));
typedef float f4v __attribute__((ext_vector_type(4)));
typedef _Float16 f16;

#define NB 8
#define CC 128
#define CB 64
#define NN 4096
#define L2E 1.4426950408889634f

// ---------------------------------------------------------------------------
// Kernel 0: pack weights into f16 MFMA-fragment order (once per launch).
// Wp[((ks*4+kc)*64 + lane)*8 + j] <- W[(ks*16+(lane&15))*CC + kc*32+((lane>>4)&3)*8 + j]
// wth pre-scaled by log2(e) for attn's exp2 softmax.
// ---------------------------------------------------------------------------
__global__ __launch_bounds__(256) void pack_w(
    const float* __restrict__ wth, const float* __restrict__ wph,
    const float* __restrict__ wg,  const float* __restrict__ wl,
    f16* __restrict__ wthp, f16* __restrict__ wphp,
    f16* __restrict__ wgp,  f16* __restrict__ wlp)
{
    const int t = blockIdx.x * 256 + threadIdx.x;      // 2048 threads
    for (int i = t; i < 8192; i += 2048){
        const int j = i & 7, lane = (i >> 3) & 63, kc = (i >> 9) & 3, ks = i >> 11;
        const int row = ks * 16 + (lane & 15);
        const int col = kc * 32 + ((lane >> 4) & 3) * 8 + j;
        wthp[i] = (f16)(wth[row * CC + col] * L2E);
        wphp[i] = (f16)(wph[row * CC + col]);
        wgp [i] = (f16)(wg [row * CC + col]);
    }
    for (int i = t; i < 8192; i += 2048){
        const int j = i & 7, lane = (i >> 3) & 63, kc = (i >> 9) & 1, cs = i >> 10;
        const int row = cs * 16 + (lane & 15);
        const int col = kc * 32 + ((lane >> 4) & 3) * 8 + j;
        wlp[i] = (f16)(wl[row * CB + col]);
    }
}

// ---------------------------------------------------------------------------
// Kernel 1: projections (unchanged).
// ---------------------------------------------------------------------------
__global__ __launch_bounds__(256) void proj_kernel(
    const float* __restrict__ x, const f16* __restrict__ wthp,
    const f16* __restrict__ wphp, const f16* __restrict__ wgp,
    f16* __restrict__ thetaT, f16* __restrict__ phiT, f16* __restrict__ gbuf)
{
    __shared__ __align__(16) f16 xT[64][136];
    __shared__ __align__(16) f16 rep[4][16 * 72];
    const int b  = blockIdx.x & 7;
    const int n0 = (blockIdx.x >> 3) << 6;
    const int t  = threadIdx.x;

    #pragma unroll
    for (int i = 0; i < 8; i++){
        int v  = t + 256 * i;
        int c  = v >> 4;
        int j0 = (v & 15) << 2;
        const f4v xv = *(const f4v*)&x[((size_t)(b * CC + c)) * NN + n0 + j0];
        #pragma unroll
        for (int jj = 0; jj < 4; jj++) xT[j0 + jj][c] = (f16)xv[jj];
    }
    __syncthreads();

    const int w = t >> 6, lane = t & 63, quad = lane >> 4, l15 = lane & 15;
    const int rrow = lane >> 3, rcol = (lane & 7) * 8;

    h8v bx[4];
    #pragma unroll
    for (int kc = 0; kc < 4; kc++)
        bx[kc] = *(const h8v*)&xT[w * 16 + l15][kc * 32 + quad * 8];

    #pragma unroll
    for (int m3 = 0; m3 < 2; m3++){
        const f16* WP = (m3 == 0) ? wthp : wphp;
        f16* OUT      = (m3 == 0) ? thetaT : phiT;
        for (int ks = 0; ks < 4; ks++){
            f4v acc = {0.f, 0.f, 0.f, 0.f};
            #pragma unroll
            for (int kc = 0; kc < 4; kc++){
                const h8v af = *(const h8v*)&WP[(ks * 4 + kc) * 512 + lane * 8];
                acc = __builtin_amdgcn_mfma_f32_16x16x32_f16(af, bx[kc], acc, 0, 0, 0);
            }
            h4v pv;
            #pragma unroll
            for (int r = 0; r < 4; r++) pv[r] = (f16)acc[r];
            *(h4v*)&rep[w][l15 * 72 + ks * 16 + quad * 4] = pv;
        }
        #pragma unroll
        for (int j = 0; j < 2; j++){
            const h8v vv = *(const h8v*)&rep[w][(rrow + 8 * j) * 72 + rcol];
            *(h8v*)&OUT[((size_t)(b * NN + n0 + w * 16 + rrow + 8 * j)) * CB + rcol] = vv;
        }
    }

    h8v bw[4];
    #pragma unroll
    for (int kc = 0; kc < 4; kc++)
        bw[kc] = *(const h8v*)&wgp[(w * 4 + kc) * 512 + lane * 8];
    for (int ns = 0; ns < 4; ns++){
        f4v acc = {0.f, 0.f, 0.f, 0.f};
        #pragma unroll
        for (int kc = 0; kc < 4; kc++){
            const h8v af = *(const h8v*)&xT[ns * 16 + l15][kc * 32 + quad * 8];
            acc = __builtin_amdgcn_mfma_f32_16x16x32_f16(af, bw[kc], acc, 0, 0, 0);
        }
        h4v pv;
        #pragma unroll
        for (int r = 0; r < 4; r++) pv[r] = (f16)acc[r];
        *(h4v*)&rep[w][l15 * 72 + ns * 16 + quad * 4] = pv;
    }
    #pragma unroll
    for (int j = 0; j < 2; j++){
        const h8v vv = *(const h8v*)&rep[w][(rrow + 8 * j) * 72 + rcol];
        *(h8v*)&gbuf[((size_t)(b * CB + w * 16 + rrow + 8 * j)) * NN + n0 + rcol] = vv;
    }
}

// ---------------------------------------------------------------------------
// Kernel 2: fused attention + final projection + residual.
// R14/R15: 16q/wave, 64q/block, grid 512 (2 blocks/CU, 2 waves/SIMD).
// phi/g MFMA fragments loaded DIRECTLY from global (L1/L2-resident tiles;
// one wave-instr = 16 fully-consumed 64B lines) -- no K-loop LDS staging,
// no K-loop barriers, waves free-run. Defer-max softmax retained (P <= 2^8).
// Only remaining K-loop LDS: wave-private P round-trip.
// ---------------------------------------------------------------------------
__global__ __launch_bounds__(256, 2) void attn_kernel(
    const f16* __restrict__ thetaT, const f16* __restrict__ phiT,
    const f16* __restrict__ gbuf, const f16* __restrict__ wlp,
    const float* __restrict__ x, float* __restrict__ out)
{
    __shared__ __align__(16) float fO[128][68];     // epilogue out-tile
    __shared__ __align__(16) f16 plds[4][16 * 72];  // per-wave P tile, then y tile

    const int b  = blockIdx.x & 7;                  // batch -> XCD swizzle
    const int q0 = (blockIdx.x >> 3) << 6;
    const int t  = threadIdx.x;
    const int w = t >> 6, lane = t & 63, quad = lane >> 4, l15 = lane & 15;
    const int n0 = q0 + w * 16;

    const size_t trow = ((size_t)(b * NN + n0 + l15)) * CB;
    const h8v a0 = *(const h8v*)&thetaT[trow + quad * 8];
    const h8v a1 = *(const h8v*)&thetaT[trow + 32 + quad * 8];

    // direct-load fragment bases: phi[key][cb], g[cb][key]
    const f16* const pph = phiT + ((size_t)(b * NN + l15)) * CB + quad * 8;
    const f16* const pgg = gbuf + ((size_t)(b * CB + l15)) * NN + quad * 8;

    float mrun = -1e30f, lrun = 0.f;
    const f4v zf = {0.f, 0.f, 0.f, 0.f};
    f4v o[4];
    #pragma unroll
    for (int tt = 0; tt < 4; tt++) o[tt] = zf;

    f16* const pw = &plds[w][0];

    for (int kb = 0; kb < 64; kb++){
        const f16* pp = pph + (size_t)(kb * 64) * CB;
        const f16* pg = pgg + kb * 64;

        // issue all 16 fragment loads up front (independent; L1/L2-served)
        h8v f0[4], f1[4], g0[4], g1[4];
        #pragma unroll
        for (int tt = 0; tt < 4; tt++){
            f0[tt] = *(const h8v*)(pp + (size_t)(tt * 16) * CB);
            f1[tt] = *(const h8v*)(pp + (size_t)(tt * 16) * CB + 32);
            g0[tt] = *(const h8v*)(pg + (size_t)(tt * 16) * NN);
            g1[tt] = *(const h8v*)(pg + (size_t)(tt * 16) * NN + 32);
        }

        // ---- S^T = phi(A) * theta(B) ----
        f4v s[4];
        #pragma unroll
        for (int tt = 0; tt < 4; tt++){
            f4v sv = zf;
            sv = __builtin_amdgcn_mfma_f32_16x16x32_f16(f0[tt], a0, sv, 0, 0, 0);
            sv = __builtin_amdgcn_mfma_f32_16x16x32_f16(f1[tt], a1, sv, 0, 0, 0);
            s[tt] = sv;
        }

        // ---- online softmax, defer-max (log2 domain; lane owns query l15) ----
        float smax = fmaxf(fmaxf(s[0][0], s[0][1]), fmaxf(s[0][2], s[0][3]));
        #pragma unroll
        for (int tt = 1; tt < 4; tt++)
            smax = fmaxf(smax, fmaxf(fmaxf(s[tt][0], s[tt][1]), fmaxf(s[tt][2], s[tt][3])));
        smax = fmaxf(smax, __shfl_xor(smax, 16));
        smax = fmaxf(smax, __shfl_xor(smax, 32));

        if (__any(smax - mrun > 8.f)){
            const float mn = fmaxf(mrun, smax);
            const float alpha = __builtin_amdgcn_exp2f(mrun - mn);
            mrun = mn;
            lrun *= alpha;
            #pragma unroll
            for (int tt = 0; tt < 4; tt++)
                #pragma unroll
                for (int r = 0; r < 4; r++)
                    o[tt][r] *= alpha;
        }

        float lsum = 0.f;
        #pragma unroll
        for (int tt = 0; tt < 4; tt++){
            h4v pv;
            #pragma unroll
            for (int r = 0; r < 4; r++){
                float p = __builtin_amdgcn_exp2f(s[tt][r] - mrun);
                lsum += p;
                pv[r] = (f16)p;
            }
            *(h4v*)&pw[l15 * 72 + tt * 16 + quad * 4] = pv;
        }
        lrun += lsum;

        const h8v pa0 = *(const h8v*)&pw[l15 * 72 + quad * 8];
        const h8v pa1 = *(const h8v*)&pw[l15 * 72 + 32 + quad * 8];

        // ---- O^T += g(A) * P^T(B) ----
        #pragma unroll
        for (int tt = 0; tt < 4; tt++){
            o[tt] = __builtin_amdgcn_mfma_f32_16x16x32_f16(g0[tt], pa0, o[tt], 0, 0, 0);
            o[tt] = __builtin_amdgcn_mfma_f32_16x16x32_f16(g1[tt], pa1, o[tt], 0, 0, 0);
        }
    }

    lrun += __shfl_xor(lrun, 16);
    lrun += __shfl_xor(lrun, 32);
    const float inv = 1.0f / lrun;

    #pragma unroll
    for (int tt = 0; tt < 4; tt++){
        h4v yv;
        #pragma unroll
        for (int r = 0; r < 4; r++) yv[r] = (f16)(o[tt][r] * inv);
        *(h4v*)&pw[l15 * 72 + tt * 16 + quad * 4] = yv;
    }

    // ---- out-GEMM: D[c][q] = wl(A) * y(B); packed wl fragments ----
    const h8v yB0 = *(const h8v*)&pw[l15 * 72 + quad * 8];
    const h8v yB1 = *(const h8v*)&pw[l15 * 72 + 32 + quad * 8];
    #pragma unroll
    for (int cs = 0; cs < 8; cs++){
        const h8v wa0 = *(const h8v*)&wlp[(cs * 2 + 0) * 512 + lane * 8];
        const h8v wa1 = *(const h8v*)&wlp[(cs * 2 + 1) * 512 + lane * 8];
        f4v acc = zf;
        acc = __builtin_amdgcn_mfma_f32_16x16x32_f16(wa0, yB0, acc, 0, 0, 0);
        acc = __builtin_amdgcn_mfma_f32_16x16x32_f16(wa1, yB1, acc, 0, 0, 0);
        #pragma unroll
        for (int r = 0; r < 4; r++)
            fO[cs * 16 + quad * 4 + r][w * 16 + l15] = acc[r];
    }
    __syncthreads();

    // ---- residual RMW: fully coalesced float4 ----
    #pragma unroll
    for (int i = 0; i < 8; i++){
        const int row = i * 16 + (t >> 4);
        const int nf  = (t & 15) * 4;
        const f4v v = *(const f4v*)&fO[row][nf];
        const size_t idx = ((size_t)(b * CC + row)) * NN + q0 + nf;
        const f4v xv = *(const f4v*)&x[idx];
        f4v ov;
        #pragma unroll
        for (int r = 0; r < 4; r++) ov[r] = v[r] + xv[r];
        *(f4v*)&out[idx] = ov;
    }
}

extern "C" void kernel_launch(void* const* d_in, const int* in_sizes, int n_in,
                              void* d_out, int out_size, void* d_ws, size_t ws_size,
                              hipStream_t stream)
{
    const float* x   = (const float*)d_in[0];
    const float* wth = (const float*)d_in[1];
    const float* wph = (const float*)d_in[2];
    const float* wg  = (const float*)d_in[3];
    const float* wl  = (const float*)d_in[4];
    float* out = (float*)d_out;

    f16* thetaT = (f16*)d_ws;
    f16* phiT   = thetaT + (size_t)NB * NN * CB;
    f16* gbuf   = phiT   + (size_t)NB * NN * CB;
    f16* wthp   = gbuf   + (size_t)NB * NN * CB;
    f16* wphp   = wthp + 8192;
    f16* wgp    = wphp + 8192;
    f16* wlp    = wgp  + 8192;

    pack_w<<<8, 256, 0, stream>>>(wth, wph, wg, wl, wthp, wphp, wgp, wlp);
    proj_kernel<<<NB * 64, 256, 0, stream>>>(x, wthp, wphp, wgp, thetaT, phiT, gbuf);
    attn_kernel<<<NB * 64, 256, 0, stream>>>(thetaT, phiT, gbuf, wlp, x, out);
}

// Round 4
// 175.028 us; speedup vs baseline: 1.7756x; 1.7756x over previous
//
#include <hip/hip_runtime.h>
#include <stdint.h>

typedef _Float16 h8v __attribute__((ext_vector_type(8)));
typedef _Float16 h4v __attribute__((ext_vector_type(4)));
typedef float f4v __attribute__((ext_vector_type(4)));
typedef _Float16 f16;

#define NB 8
#define CC 128
#define CB 64
#define NN 4096
#define L2E 1.4426950408889634f

#define GLD(gp, lp) __builtin_amdgcn_global_load_lds( \
    (const __attribute__((address_space(1))) void*)(gp), \
    (__attribute__((address_space(3))) void*)(lp), 16, 0, 0)

// ---------------------------------------------------------------------------
// Kernel 0: pack weights into f16 MFMA-fragment order (once per launch).
// Wp[((ks*4+kc)*64 + lane)*8 + j] <- W[(ks*16+(lane&15))*CC + kc*32+((lane>>4)&3)*8 + j]
// wth pre-scaled by log2(e) for attn's exp2 softmax.
// ---------------------------------------------------------------------------
__global__ __launch_bounds__(256) void pack_w(
    const float* __restrict__ wth, const float* __restrict__ wph,
    const float* __restrict__ wg,  const float* __restrict__ wl,
    f16* __restrict__ wthp, f16* __restrict__ wphp,
    f16* __restrict__ wgp,  f16* __restrict__ wlp)
{
    const int t = blockIdx.x * 256 + threadIdx.x;      // 2048 threads
    for (int i = t; i < 8192; i += 2048){
        const int j = i & 7, lane = (i >> 3) & 63, kc = (i >> 9) & 3, ks = i >> 11;
        const int row = ks * 16 + (lane & 15);
        const int col = kc * 32 + ((lane >> 4) & 3) * 8 + j;
        wthp[i] = (f16)(wth[row * CC + col] * L2E);
        wphp[i] = (f16)(wph[row * CC + col]);
        wgp [i] = (f16)(wg [row * CC + col]);
    }
    for (int i = t; i < 8192; i += 2048){
        const int j = i & 7, lane = (i >> 3) & 63, kc = (i >> 9) & 1, cs = i >> 10;
        const int row = cs * 16 + (lane & 15);
        const int col = kc * 32 + ((lane >> 4) & 3) * 8 + j;
        wlp[i] = (f16)(wl[row * CB + col]);
    }
}

// ---------------------------------------------------------------------------
// Kernel 1: projections (unchanged, proven).
// ---------------------------------------------------------------------------
__global__ __launch_bounds__(256) void proj_kernel(
    const float* __restrict__ x, const f16* __restrict__ wthp,
    const f16* __restrict__ wphp, const f16* __restrict__ wgp,
    f16* __restrict__ thetaT, f16* __restrict__ phiT, f16* __restrict__ gbuf)
{
    __shared__ __align__(16) f16 xT[64][136];
    __shared__ __align__(16) f16 rep[4][16 * 72];
    const int b  = blockIdx.x & 7;
    const int n0 = (blockIdx.x >> 3) << 6;
    const int t  = threadIdx.x;

    #pragma unroll
    for (int i = 0; i < 8; i++){
        int v  = t + 256 * i;
        int c  = v >> 4;
        int j0 = (v & 15) << 2;
        const f4v xv = *(const f4v*)&x[((size_t)(b * CC + c)) * NN + n0 + j0];
        #pragma unroll
        for (int jj = 0; jj < 4; jj++) xT[j0 + jj][c] = (f16)xv[jj];
    }
    __syncthreads();

    const int w = t >> 6, lane = t & 63, quad = lane >> 4, l15 = lane & 15;
    const int rrow = lane >> 3, rcol = (lane & 7) * 8;

    h8v bx[4];
    #pragma unroll
    for (int kc = 0; kc < 4; kc++)
        bx[kc] = *(const h8v*)&xT[w * 16 + l15][kc * 32 + quad * 8];

    #pragma unroll
    for (int m3 = 0; m3 < 2; m3++){
        const f16* WP = (m3 == 0) ? wthp : wphp;
        f16* OUT      = (m3 == 0) ? thetaT : phiT;
        for (int ks = 0; ks < 4; ks++){
            f4v acc = {0.f, 0.f, 0.f, 0.f};
            #pragma unroll
            for (int kc = 0; kc < 4; kc++){
                const h8v af = *(const h8v*)&WP[(ks * 4 + kc) * 512 + lane * 8];
                acc = __builtin_amdgcn_mfma_f32_16x16x32_f16(af, bx[kc], acc, 0, 0, 0);
            }
            h4v pv;
            #pragma unroll
            for (int r = 0; r < 4; r++) pv[r] = (f16)acc[r];
            *(h4v*)&rep[w][l15 * 72 + ks * 16 + quad * 4] = pv;
        }
        #pragma unroll
        for (int j = 0; j < 2; j++){
            const h8v vv = *(const h8v*)&rep[w][(rrow + 8 * j) * 72 + rcol];
            *(h8v*)&OUT[((size_t)(b * NN + n0 + w * 16 + rrow + 8 * j)) * CB + rcol] = vv;
        }
    }

    h8v bw[4];
    #pragma unroll
    for (int kc = 0; kc < 4; kc++)
        bw[kc] = *(const h8v*)&wgp[(w * 4 + kc) * 512 + lane * 8];
    for (int ns = 0; ns < 4; ns++){
        f4v acc = {0.f, 0.f, 0.f, 0.f};
        #pragma unroll
        for (int kc = 0; kc < 4; kc++){
            const h8v af = *(const h8v*)&xT[ns * 16 + l15][kc * 32 + quad * 8];
            acc = __builtin_amdgcn_mfma_f32_16x16x32_f16(af, bw[kc], acc, 0, 0, 0);
        }
        h4v pv;
        #pragma unroll
        for (int r = 0; r < 4; r++) pv[r] = (f16)acc[r];
        *(h4v*)&rep[w][l15 * 72 + ns * 16 + quad * 4] = pv;
    }
    #pragma unroll
    for (int j = 0; j < 2; j++){
        const h8v vv = *(const h8v*)&rep[w][(rrow + 8 * j) * 72 + rcol];
        *(h8v*)&gbuf[((size_t)(b * CB + w * 16 + rrow + 8 * j)) * NN + n0 + rcol] = vv;
    }
}

// ---------------------------------------------------------------------------
// Kernel 2: fused attention + final projection + residual.
// R16 = R12 structure (16q/wave, 64q/block, grid 512, dbuf LDS, 1 barrier/iter)
//  + global_load_lds staging (linear lane*16 dest; XOR-swizzled GLOBAL source,
//    same XOR on read side -- rule 21 both-sides swizzle; unpadded [64][64])
//  + defer-max softmax (skip rescale unless __any(smax-mrun > 8); P <= 2^8).
// ---------------------------------------------------------------------------
union StageOrOut {
    struct { f16 ph[2][64 * 64]; f16 g[2][64 * 64]; } s;   // 32768 B (K-loop)
    float fO[128][68];                                      // 34816 B (epilogue)
};

__global__ __launch_bounds__(256, 2) void attn_kernel(
    const f16* __restrict__ thetaT, const f16* __restrict__ phiT,
    const f16* __restrict__ gbuf, const f16* __restrict__ wlp,
    const float* __restrict__ x, float* __restrict__ out)
{
    __shared__ __align__(16) StageOrOut sh;
    __shared__ __align__(16) f16 plds[4][16 * 72];  // per-wave P tile, then y tile

    const int b  = blockIdx.x & 7;                  // batch -> XCD swizzle
    const int q0 = (blockIdx.x >> 3) << 6;
    const int t  = threadIdx.x;
    const int w = t >> 6, lane = t & 63, quad = lane >> 4, l15 = lane & 15;
    const int n0 = q0 + w * 16;

    const size_t trow = ((size_t)(b * NN + n0 + l15)) * CB;
    const h8v a0 = *(const h8v*)&thetaT[trow + quad * 8];
    const h8v a1 = *(const h8v*)&thetaT[trow + 32 + quad * 8];

    // gl_lds staging: lane's LDS slot (row = 16w + 8i + (lane>>3), slot lane&7)
    // holds col-block cb = (lane&7) ^ (row&7); row&7 == lane>>3 for both i.
    const int srow = w * 16 + (lane >> 3);
    const int scb  = (lane & 7) ^ (lane >> 3);
    const f16* const pphB = phiT + ((size_t)(b * NN + srow)) * CB + scb * 8;
    const f16* const pggB = gbuf + ((size_t)(b * CB + srow)) * NN + scb * 8;

    // swizzled read offsets within a 64-f16 row (read rows are tt*16 + l15)
    const int so0 = (quad ^ (l15 & 7)) * 8;
    const int so1 = so0 ^ 32;

    auto STAGE = [&](int nb, int kb){
        const f16* s0 = pphB + (size_t)(kb * 64) * CB;
        const f16* s2 = pggB + kb * 64;
        f16* d0 = &sh.s.ph[nb][w * 1024];
        f16* d1 = &sh.s.g [nb][w * 1024];
        GLD(s0,            d0);
        GLD(s0 + 8 * CB,   d0 + 512);
        GLD(s2,            d1);
        GLD(s2 + 8 * NN,   d1 + 512);
    };

    STAGE(0, 0);

    float mrun = -1e30f, lrun = 0.f;
    const f4v zf = {0.f, 0.f, 0.f, 0.f};
    f4v o[4];
    #pragma unroll
    for (int tt = 0; tt < 4; tt++) o[tt] = zf;

    f16* const pw = &plds[w][0];

    for (int kb = 0; kb < 64; kb++){
        const int pb = kb & 1;
        __syncthreads();                       // drains vmcnt: buf pb staged
        if (kb < 63) STAGE(pb ^ 1, kb + 1);    // async prefetch next tile

        // ---- S^T = phi(A) * theta(B) ----
        f4v s[4];
        #pragma unroll
        for (int tt = 0; tt < 4; tt++){
            const f16* pr = &sh.s.ph[pb][(tt * 16 + l15) * 64];
            const h8v pb0 = *(const h8v*)(pr + so0);
            const h8v pb1 = *(const h8v*)(pr + so1);
            f4v sv = zf;
            sv = __builtin_amdgcn_mfma_f32_16x16x32_f16(pb0, a0, sv, 0, 0, 0);
            sv = __builtin_amdgcn_mfma_f32_16x16x32_f16(pb1, a1, sv, 0, 0, 0);
            s[tt] = sv;
        }

        // ---- online softmax, defer-max (log2 domain; lane owns query l15) ----
        float smax = fmaxf(fmaxf(s[0][0], s[0][1]), fmaxf(s[0][2], s[0][3]));
        #pragma unroll
        for (int tt = 1; tt < 4; tt++)
            smax = fmaxf(smax, fmaxf(fmaxf(s[tt][0], s[tt][1]), fmaxf(s[tt][2], s[tt][3])));
        smax = fmaxf(smax, __shfl_xor(smax, 16));
        smax = fmaxf(smax, __shfl_xor(smax, 32));

        if (__any(smax - mrun > 8.f)){
            const float mn = fmaxf(mrun, smax);
            const float alpha = __builtin_amdgcn_exp2f(mrun - mn);
            mrun = mn;
            lrun *= alpha;
            #pragma unroll
            for (int tt = 0; tt < 4; tt++)
                #pragma unroll
                for (int r = 0; r < 4; r++)
                    o[tt][r] *= alpha;
        }

        float lsum = 0.f;
        #pragma unroll
        for (int tt = 0; tt < 4; tt++){
            h4v pv;
            #pragma unroll
            for (int r = 0; r < 4; r++){
                float p = __builtin_amdgcn_exp2f(s[tt][r] - mrun);
                lsum += p;
                pv[r] = (f16)p;
            }
            *(h4v*)&pw[l15 * 72 + tt * 16 + quad * 4] = pv;
        }
        lrun += lsum;

        const h8v pa0 = *(const h8v*)&pw[l15 * 72 + quad * 8];
        const h8v pa1 = *(const h8v*)&pw[l15 * 72 + 32 + quad * 8];

        // ---- O^T += g(A) * P^T(B) ----
        #pragma unroll
        for (int tt = 0; tt < 4; tt++){
            const f16* gr = &sh.s.g[pb][(tt * 16 + l15) * 64];
            const h8v gb0 = *(const h8v*)(gr + so0);
            const h8v gb1 = *(const h8v*)(gr + so1);
            o[tt] = __builtin_amdgcn_mfma_f32_16x16x32_f16(gb0, pa0, o[tt], 0, 0, 0);
            o[tt] = __builtin_amdgcn_mfma_f32_16x16x32_f16(gb1, pa1, o[tt], 0, 0, 0);
        }
    }

    lrun += __shfl_xor(lrun, 16);
    lrun += __shfl_xor(lrun, 32);
    const float inv = 1.0f / lrun;

    #pragma unroll
    for (int tt = 0; tt < 4; tt++){
        h4v yv;
        #pragma unroll
        for (int r = 0; r < 4; r++) yv[r] = (f16)(o[tt][r] * inv);
        *(h4v*)&pw[l15 * 72 + tt * 16 + quad * 4] = yv;
    }

    __syncthreads();   // staging region dead -> overlay fO

    // ---- out-GEMM: D[c][q] = wl(A) * y(B); packed wl fragments ----
    const h8v yB0 = *(const h8v*)&pw[l15 * 72 + quad * 8];
    const h8v yB1 = *(const h8v*)&pw[l15 * 72 + 32 + quad * 8];
    #pragma unroll
    for (int cs = 0; cs < 8; cs++){
        const h8v wa0 = *(const h8v*)&wlp[(cs * 2 + 0) * 512 + lane * 8];
        const h8v wa1 = *(const h8v*)&wlp[(cs * 2 + 1) * 512 + lane * 8];
        f4v acc = zf;
        acc = __builtin_amdgcn_mfma_f32_16x16x32_f16(wa0, yB0, acc, 0, 0, 0);
        acc = __builtin_amdgcn_mfma_f32_16x16x32_f16(wa1, yB1, acc, 0, 0, 0);
        #pragma unroll
        for (int r = 0; r < 4; r++)
            sh.fO[cs * 16 + quad * 4 + r][w * 16 + l15] = acc[r];
    }
    __syncthreads();

    // ---- residual RMW: fully coalesced float4 ----
    #pragma unroll
    for (int i = 0; i < 8; i++){
        const int row = i * 16 + (t >> 4);
        const int nf  = (t & 15) * 4;
        const f4v v = *(const f4v*)&sh.fO[row][nf];
        const size_t idx = ((size_t)(b * CC + row)) * NN + q0 + nf;
        const f4v xv = *(const f4v*)&x[idx];
        f4v ov;
        #pragma unroll
        for (int r = 0; r < 4; r++) ov[r] = v[r] + xv[r];
        *(f4v*)&out[idx] = ov;
    }
}

extern "C" void kernel_launch(void* const* d_in, const int* in_sizes, int n_in,
                              void* d_out, int out_size, void* d_ws, size_t ws_size,
                              hipStream_t stream)
{
    const float* x   = (const float*)d_in[0];
    const float* wth = (const float*)d_in[1];
    const float* wph = (const float*)d_in[2];
    const float* wg  = (const float*)d_in[3];
    const float* wl  = (const float*)d_in[4];
    float* out = (float*)d_out;

    f16* thetaT = (f16*)d_ws;
    f16* phiT   = thetaT + (size_t)NB * NN * CB;
    f16* gbuf   = phiT   + (size_t)NB * NN * CB;
    f16* wthp   = gbuf   + (size_t)NB * NN * CB;
    f16* wphp   = wthp + 8192;
    f16* wgp    = wphp + 8192;
    f16* wlp    = wgp  + 8192;

    pack_w<<<8, 256, 0, stream>>>(wth, wph, wg, wl, wthp, wphp, wgp, wlp);
    proj_kernel<<<NB * 64, 256, 0, stream>>>(x, wthp, wphp, wgp, thetaT, phiT, gbuf);
    attn_kernel<<<NB * 64, 256, 0, stream>>>(thetaT, phiT, gbuf, wlp, x, out);
}

// Round 5
// 156.472 us; speedup vs baseline: 1.9862x; 1.1186x over previous
//
#include <hip/hip_runtime.h>
#include <stdint.h>

typedef _Float16 h8v __attribute__((ext_vector_type(8)));
typedef _Float16 h4v __attribute__((ext_vector_type(4)));
typedef float f4v __attribute__((ext_vector_type(4)));
typedef _Float16 f16;

#define NB 8
#define CC 128
#define CB 64
#define NN 4096
#define L2E 1.4426950408889634f

#define GLD(gp, lp) __builtin_amdgcn_global_load_lds( \
    (const __attribute__((address_space(1))) void*)(gp), \
    (__attribute__((address_space(3))) void*)(lp), 16, 0, 0)

#define WAITV4() asm volatile("s_waitcnt vmcnt(4)" ::: "memory")
#define WAITV0() asm volatile("s_waitcnt vmcnt(0)" ::: "memory")
#define WAITL0() asm volatile("s_waitcnt lgkmcnt(0)" ::: "memory")

// ---------------------------------------------------------------------------
// Kernel 0: pack weights into f16 MFMA-fragment order (once per launch).
// wth pre-scaled by log2(e) for attn's exp2 softmax.
// ---------------------------------------------------------------------------
__global__ __launch_bounds__(256) void pack_w(
    const float* __restrict__ wth, const float* __restrict__ wph,
    const float* __restrict__ wg,  const float* __restrict__ wl,
    f16* __restrict__ wthp, f16* __restrict__ wphp,
    f16* __restrict__ wgp,  f16* __restrict__ wlp)
{
    const int t = blockIdx.x * 256 + threadIdx.x;      // 2048 threads
    for (int i = t; i < 8192; i += 2048){
        const int j = i & 7, lane = (i >> 3) & 63, kc = (i >> 9) & 3, ks = i >> 11;
        const int row = ks * 16 + (lane & 15);
        const int col = kc * 32 + ((lane >> 4) & 3) * 8 + j;
        wthp[i] = (f16)(wth[row * CC + col] * L2E);
        wphp[i] = (f16)(wph[row * CC + col]);
        wgp [i] = (f16)(wg [row * CC + col]);
    }
    for (int i = t; i < 8192; i += 2048){
        const int j = i & 7, lane = (i >> 3) & 63, kc = (i >> 9) & 1, cs = i >> 10;
        const int row = cs * 16 + (lane & 15);
        const int col = kc * 32 + ((lane >> 4) & 3) * 8 + j;
        wlp[i] = (f16)(wl[row * CB + col]);
    }
}

// ---------------------------------------------------------------------------
// Kernel 1: projections (unchanged, proven).
// ---------------------------------------------------------------------------
__global__ __launch_bounds__(256) void proj_kernel(
    const float* __restrict__ x, const f16* __restrict__ wthp,
    const f16* __restrict__ wphp, const f16* __restrict__ wgp,
    f16* __restrict__ thetaT, f16* __restrict__ phiT, f16* __restrict__ gbuf)
{
    __shared__ __align__(16) f16 xT[64][136];
    __shared__ __align__(16) f16 rep[4][16 * 72];
    const int b  = blockIdx.x & 7;
    const int n0 = (blockIdx.x >> 3) << 6;
    const int t  = threadIdx.x;

    #pragma unroll
    for (int i = 0; i < 8; i++){
        int v  = t + 256 * i;
        int c  = v >> 4;
        int j0 = (v & 15) << 2;
        const f4v xv = *(const f4v*)&x[((size_t)(b * CC + c)) * NN + n0 + j0];
        #pragma unroll
        for (int jj = 0; jj < 4; jj++) xT[j0 + jj][c] = (f16)xv[jj];
    }
    __syncthreads();

    const int w = t >> 6, lane = t & 63, quad = lane >> 4, l15 = lane & 15;
    const int rrow = lane >> 3, rcol = (lane & 7) * 8;

    h8v bx[4];
    #pragma unroll
    for (int kc = 0; kc < 4; kc++)
        bx[kc] = *(const h8v*)&xT[w * 16 + l15][kc * 32 + quad * 8];

    #pragma unroll
    for (int m3 = 0; m3 < 2; m3++){
        const f16* WP = (m3 == 0) ? wthp : wphp;
        f16* OUT      = (m3 == 0) ? thetaT : phiT;
        for (int ks = 0; ks < 4; ks++){
            f4v acc = {0.f, 0.f, 0.f, 0.f};
            #pragma unroll
            for (int kc = 0; kc < 4; kc++){
                const h8v af = *(const h8v*)&WP[(ks * 4 + kc) * 512 + lane * 8];
                acc = __builtin_amdgcn_mfma_f32_16x16x32_f16(af, bx[kc], acc, 0, 0, 0);
            }
            h4v pv;
            #pragma unroll
            for (int r = 0; r < 4; r++) pv[r] = (f16)acc[r];
            *(h4v*)&rep[w][l15 * 72 + ks * 16 + quad * 4] = pv;
        }
        #pragma unroll
        for (int j = 0; j < 2; j++){
            const h8v vv = *(const h8v*)&rep[w][(rrow + 8 * j) * 72 + rcol];
            *(h8v*)&OUT[((size_t)(b * NN + n0 + w * 16 + rrow + 8 * j)) * CB + rcol] = vv;
        }
    }

    h8v bw[4];
    #pragma unroll
    for (int kc = 0; kc < 4; kc++)
        bw[kc] = *(const h8v*)&wgp[(w * 4 + kc) * 512 + lane * 8];
    for (int ns = 0; ns < 4; ns++){
        f4v acc = {0.f, 0.f, 0.f, 0.f};
        #pragma unroll
        for (int kc = 0; kc < 4; kc++){
            const h8v af = *(const h8v*)&xT[ns * 16 + l15][kc * 32 + quad * 8];
            acc = __builtin_amdgcn_mfma_f32_16x16x32_f16(af, bw[kc], acc, 0, 0, 0);
        }
        h4v pv;
        #pragma unroll
        for (int r = 0; r < 4; r++) pv[r] = (f16)acc[r];
        *(h4v*)&rep[w][l15 * 72 + ns * 16 + quad * 4] = pv;
    }
    #pragma unroll
    for (int j = 0; j < 2; j++){
        const h8v vv = *(const h8v*)&rep[w][(rrow + 8 * j) * 72 + rcol];
        *(h8v*)&gbuf[((size_t)(b * CB + w * 16 + rrow + 8 * j)) * NN + n0 + rcol] = vv;
    }
}

// ---------------------------------------------------------------------------
// Kernel 2: fused attention + final projection + residual.
// R17 = R16 (gl_lds staging, both-sides XOR swizzle, defer-max)
//  + TRIPLE-buffer staging, raw s_barrier, counted vmcnt(4) (T3/T4-lite):
//    loads never drain to 0 in the main loop; prefetch depth = 2 iters.
//  + s_setprio(1) around the MFMA clusters (T5).
// ---------------------------------------------------------------------------
union StageOrOut {
    struct { f16 ph[3][64 * 64]; f16 g[3][64 * 64]; } s;   // 49152 B (K-loop)
    float fO[128][68];                                      // 34816 B (epilogue)
};

__global__ __launch_bounds__(256, 2) void attn_kernel(
    const f16* __restrict__ thetaT, const f16* __restrict__ phiT,
    const f16* __restrict__ gbuf, const f16* __restrict__ wlp,
    const float* __restrict__ x, float* __restrict__ out)
{
    __shared__ __align__(16) StageOrOut sh;
    __shared__ __align__(16) f16 plds[4][16 * 72];  // per-wave P tile, then y tile

    const int b  = blockIdx.x & 7;                  // batch -> XCD swizzle
    const int q0 = (blockIdx.x >> 3) << 6;
    const int t  = threadIdx.x;
    const int w = t >> 6, lane = t & 63, quad = lane >> 4, l15 = lane & 15;
    const int n0 = q0 + w * 16;

    const size_t trow = ((size_t)(b * NN + n0 + l15)) * CB;
    const h8v a0 = *(const h8v*)&thetaT[trow + quad * 8];
    const h8v a1 = *(const h8v*)&thetaT[trow + 32 + quad * 8];

    // gl_lds staging: lane's LDS slot (row = 16w + 8i + (lane>>3), slot lane&7)
    // holds col-block cb = (lane&7) ^ (row&7); row&7 == lane>>3 for both i.
    const int srow = w * 16 + (lane >> 3);
    const int scb  = (lane & 7) ^ (lane >> 3);
    const f16* const pphB = phiT + ((size_t)(b * NN + srow)) * CB + scb * 8;
    const f16* const pggB = gbuf + ((size_t)(b * CB + srow)) * NN + scb * 8;

    // swizzled read offsets within a 64-f16 row (read rows are tt*16 + l15)
    const int so0 = (quad ^ (l15 & 7)) * 8;
    const int so1 = so0 ^ 32;

    auto STAGE = [&](int nb, int kb){
        const f16* s0 = pphB + (size_t)(kb * 64) * CB;
        const f16* s2 = pggB + kb * 64;
        f16* d0 = &sh.s.ph[nb][w * 1024];
        f16* d1 = &sh.s.g [nb][w * 1024];
        GLD(s0,            d0);
        GLD(s0 + 8 * CB,   d0 + 512);
        GLD(s2,            d1);
        GLD(s2 + 8 * NN,   d1 + 512);
    };

    STAGE(0, 0);
    STAGE(1, 1);

    float mrun = -1e30f, lrun = 0.f;
    const f4v zf = {0.f, 0.f, 0.f, 0.f};
    f4v o[4];
    #pragma unroll
    for (int tt = 0; tt < 4; tt++) o[tt] = zf;

    f16* const pw = &plds[w][0];

    int pb = 0;                                  // kb % 3
    for (int kb = 0; kb < 64; kb++){
        // tile kb's 4 loads landed; tile kb+1's 4 stay in flight (never drain
        // vmcnt to 0 mid-loop -- T4). lgkm(0): our reads of the buffer about
        // to be overwritten are complete before we cross the barrier.
        if (kb < 63) WAITV4(); else WAITV0();
        WAITL0();
        __builtin_amdgcn_s_barrier();
        asm volatile("" ::: "memory");
        if (kb < 62) STAGE(pb == 0 ? 2 : pb - 1, kb + 2);   // buf (kb+2)%3

        // ---- S^T = phi(A) * theta(B) ----
        f4v s[4];
        __builtin_amdgcn_s_setprio(1);
        #pragma unroll
        for (int tt = 0; tt < 4; tt++){
            const f16* pr = &sh.s.ph[pb][(tt * 16 + l15) * 64];
            const h8v pb0 = *(const h8v*)(pr + so0);
            const h8v pb1 = *(const h8v*)(pr + so1);
            f4v sv = zf;
            sv = __builtin_amdgcn_mfma_f32_16x16x32_f16(pb0, a0, sv, 0, 0, 0);
            sv = __builtin_amdgcn_mfma_f32_16x16x32_f16(pb1, a1, sv, 0, 0, 0);
            s[tt] = sv;
        }
        __builtin_amdgcn_s_setprio(0);

        // ---- online softmax, defer-max (log2 domain; lane owns query l15) ----
        float smax = fmaxf(fmaxf(s[0][0], s[0][1]), fmaxf(s[0][2], s[0][3]));
        #pragma unroll
        for (int tt = 1; tt < 4; tt++)
            smax = fmaxf(smax, fmaxf(fmaxf(s[tt][0], s[tt][1]), fmaxf(s[tt][2], s[tt][3])));
        smax = fmaxf(smax, __shfl_xor(smax, 16));
        smax = fmaxf(smax, __shfl_xor(smax, 32));

        if (__any(smax - mrun > 8.f)){
            const float mn = fmaxf(mrun, smax);
            const float alpha = __builtin_amdgcn_exp2f(mrun - mn);
            mrun = mn;
            lrun *= alpha;
            #pragma unroll
            for (int tt = 0; tt < 4; tt++)
                #pragma unroll
                for (int r = 0; r < 4; r++)
                    o[tt][r] *= alpha;
        }

        float lsum = 0.f;
        #pragma unroll
        for (int tt = 0; tt < 4; tt++){
            h4v pv;
            #pragma unroll
            for (int r = 0; r < 4; r++){
                float p = __builtin_amdgcn_exp2f(s[tt][r] - mrun);
                lsum += p;
                pv[r] = (f16)p;
            }
            *(h4v*)&pw[l15 * 72 + tt * 16 + quad * 4] = pv;
        }
        lrun += lsum;

        const h8v pa0 = *(const h8v*)&pw[l15 * 72 + quad * 8];
        const h8v pa1 = *(const h8v*)&pw[l15 * 72 + 32 + quad * 8];

        // ---- O^T += g(A) * P^T(B) ----
        __builtin_amdgcn_s_setprio(1);
        #pragma unroll
        for (int tt = 0; tt < 4; tt++){
            const f16* gr = &sh.s.g[pb][(tt * 16 + l15) * 64];
            const h8v gb0 = *(const h8v*)(gr + so0);
            const h8v gb1 = *(const h8v*)(gr + so1);
            o[tt] = __builtin_amdgcn_mfma_f32_16x16x32_f16(gb0, pa0, o[tt], 0, 0, 0);
            o[tt] = __builtin_amdgcn_mfma_f32_16x16x32_f16(gb1, pa1, o[tt], 0, 0, 0);
        }
        __builtin_amdgcn_s_setprio(0);

        pb = (pb == 2) ? 0 : pb + 1;
    }

    lrun += __shfl_xor(lrun, 16);
    lrun += __shfl_xor(lrun, 32);
    const float inv = 1.0f / lrun;

    #pragma unroll
    for (int tt = 0; tt < 4; tt++){
        h4v yv;
        #pragma unroll
        for (int r = 0; r < 4; r++) yv[r] = (f16)(o[tt][r] * inv);
        *(h4v*)&pw[l15 * 72 + tt * 16 + quad * 4] = yv;
    }

    __syncthreads();   // full drain; staging region dead -> overlay fO

    // ---- out-GEMM: D[c][q] = wl(A) * y(B); packed wl fragments ----
    const h8v yB0 = *(const h8v*)&pw[l15 * 72 + quad * 8];
    const h8v yB1 = *(const h8v*)&pw[l15 * 72 + 32 + quad * 8];
    #pragma unroll
    for (int cs = 0; cs < 8; cs++){
        const h8v wa0 = *(const h8v*)&wlp[(cs * 2 + 0) * 512 + lane * 8];
        const h8v wa1 = *(const h8v*)&wlp[(cs * 2 + 1) * 512 + lane * 8];
        f4v acc = zf;
        acc = __builtin_amdgcn_mfma_f32_16x16x32_f16(wa0, yB0, acc, 0, 0, 0);
        acc = __builtin_amdgcn_mfma_f32_16x16x32_f16(wa1, yB1, acc, 0, 0, 0);
        #pragma unroll
        for (int r = 0; r < 4; r++)
            sh.fO[cs * 16 + quad * 4 + r][w * 16 + l15] = acc[r];
    }
    __syncthreads();

    // ---- residual RMW: fully coalesced float4 ----
    #pragma unroll
    for (int i = 0; i < 8; i++){
        const int row = i * 16 + (t >> 4);
        const int nf  = (t & 15) * 4;
        const f4v v = *(const f4v*)&sh.fO[row][nf];
        const size_t idx = ((size_t)(b * CC + row)) * NN + q0 + nf;
        const f4v xv = *(const f4v*)&x[idx];
        f4v ov;
        #pragma unroll
        for (int r = 0; r < 4; r++) ov[r] = v[r] + xv[r];
        *(f4v*)&out[idx] = ov;
    }
}

extern "C" void kernel_launch(void* const* d_in, const int* in_sizes, int n_in,
                              void* d_out, int out_size, void* d_ws, size_t ws_size,
                              hipStream_t stream)
{
    const float* x   = (const float*)d_in[0];
    const float* wth = (const float*)d_in[1];
    const float* wph = (const float*)d_in[2];
    const float* wg  = (const float*)d_in[3];
    const float* wl  = (const float*)d_in[4];
    float* out = (float*)d_out;

    f16* thetaT = (f16*)d_ws;
    f16* phiT   = thetaT + (size_t)NB * NN * CB;
    f16* gbuf   = phiT   + (size_t)NB * NN * CB;
    f16* wthp   = gbuf   + (size_t)NB * NN * CB;
    f16* wphp   = wthp + 8192;
    f16* wgp    = wphp + 8192;
    f16* wlp    = wgp  + 8192;

    pack_w<<<8, 256, 0, stream>>>(wth, wph, wg, wl, wthp, wphp, wgp, wlp);
    proj_kernel<<<NB * 64, 256, 0, stream>>>(x, wthp, wphp, wgp, thetaT, phiT, gbuf);
    attn_kernel<<<NB * 64, 256, 0, stream>>>(thetaT, phiT, gbuf, wlp, x, out);
}

// Round 6
// 150.728 us; speedup vs baseline: 2.0619x; 1.0381x over previous
//
#include <hip/hip_runtime.h>
#include <stdint.h>

typedef _Float16 h8v __attribute__((ext_vector_type(8)));
typedef _Float16 h4v __attribute__((ext_vector_type(4)));
typedef float f4v __attribute__((ext_vector_type(4)));
typedef _Float16 f16;

#define NB 8
#define CC 128
#define CB 64
#define NN 4096
#define L2E 1.4426950408889634f

#define GLD(gp, lp) __builtin_amdgcn_global_load_lds( \
    (const __attribute__((address_space(1))) void*)(gp), \
    (__attribute__((address_space(3))) void*)(lp), 16, 0, 0)

#define WAITV2() asm volatile("s_waitcnt vmcnt(2)" ::: "memory")
#define WAITV0() asm volatile("s_waitcnt vmcnt(0)" ::: "memory")
#define WAITL0() asm volatile("s_waitcnt lgkmcnt(0)" ::: "memory")

// ---------------------------------------------------------------------------
// Kernel 0: pack weights into f16 MFMA-fragment order (once per launch).
// wth pre-scaled by log2(e) for attn's exp2 softmax.
// ---------------------------------------------------------------------------
__global__ __launch_bounds__(256) void pack_w(
    const float* __restrict__ wth, const float* __restrict__ wph,
    const float* __restrict__ wg,  const float* __restrict__ wl,
    f16* __restrict__ wthp, f16* __restrict__ wphp,
    f16* __restrict__ wgp,  f16* __restrict__ wlp)
{
    const int t = blockIdx.x * 256 + threadIdx.x;      // 2048 threads
    for (int i = t; i < 8192; i += 2048){
        const int j = i & 7, lane = (i >> 3) & 63, kc = (i >> 9) & 3, ks = i >> 11;
        const int row = ks * 16 + (lane & 15);
        const int col = kc * 32 + ((lane >> 4) & 3) * 8 + j;
        wthp[i] = (f16)(wth[row * CC + col] * L2E);
        wphp[i] = (f16)(wph[row * CC + col]);
        wgp [i] = (f16)(wg [row * CC + col]);
    }
    for (int i = t; i < 8192; i += 2048){
        const int j = i & 7, lane = (i >> 3) & 63, kc = (i >> 9) & 1, cs = i >> 10;
        const int row = cs * 16 + (lane & 15);
        const int col = kc * 32 + ((lane >> 4) & 3) * 8 + j;
        wlp[i] = (f16)(wl[row * CB + col]);
    }
}

// ---------------------------------------------------------------------------
// Kernel 1: projections (unchanged, proven).
// ---------------------------------------------------------------------------
__global__ __launch_bounds__(256) void proj_kernel(
    const float* __restrict__ x, const f16* __restrict__ wthp,
    const f16* __restrict__ wphp, const f16* __restrict__ wgp,
    f16* __restrict__ thetaT, f16* __restrict__ phiT, f16* __restrict__ gbuf)
{
    __shared__ __align__(16) f16 xT[64][136];
    __shared__ __align__(16) f16 rep[4][16 * 72];
    const int b  = blockIdx.x & 7;
    const int n0 = (blockIdx.x >> 3) << 6;
    const int t  = threadIdx.x;

    #pragma unroll
    for (int i = 0; i < 8; i++){
        int v  = t + 256 * i;
        int c  = v >> 4;
        int j0 = (v & 15) << 2;
        const f4v xv = *(const f4v*)&x[((size_t)(b * CC + c)) * NN + n0 + j0];
        #pragma unroll
        for (int jj = 0; jj < 4; jj++) xT[j0 + jj][c] = (f16)xv[jj];
    }
    __syncthreads();

    const int w = t >> 6, lane = t & 63, quad = lane >> 4, l15 = lane & 15;
    const int rrow = lane >> 3, rcol = (lane & 7) * 8;

    h8v bx[4];
    #pragma unroll
    for (int kc = 0; kc < 4; kc++)
        bx[kc] = *(const h8v*)&xT[w * 16 + l15][kc * 32 + quad * 8];

    #pragma unroll
    for (int m3 = 0; m3 < 2; m3++){
        const f16* WP = (m3 == 0) ? wthp : wphp;
        f16* OUT      = (m3 == 0) ? thetaT : phiT;
        for (int ks = 0; ks < 4; ks++){
            f4v acc = {0.f, 0.f, 0.f, 0.f};
            #pragma unroll
            for (int kc = 0; kc < 4; kc++){
                const h8v af = *(const h8v*)&WP[(ks * 4 + kc) * 512 + lane * 8];
                acc = __builtin_amdgcn_mfma_f32_16x16x32_f16(af, bx[kc], acc, 0, 0, 0);
            }
            h4v pv;
            #pragma unroll
            for (int r = 0; r < 4; r++) pv[r] = (f16)acc[r];
            *(h4v*)&rep[w][l15 * 72 + ks * 16 + quad * 4] = pv;
        }
        #pragma unroll
        for (int j = 0; j < 2; j++){
            const h8v vv = *(const h8v*)&rep[w][(rrow + 8 * j) * 72 + rcol];
            *(h8v*)&OUT[((size_t)(b * NN + n0 + w * 16 + rrow + 8 * j)) * CB + rcol] = vv;
        }
    }

    h8v bw[4];
    #pragma unroll
    for (int kc = 0; kc < 4; kc++)
        bw[kc] = *(const h8v*)&wgp[(w * 4 + kc) * 512 + lane * 8];
    for (int ns = 0; ns < 4; ns++){
        f4v acc = {0.f, 0.f, 0.f, 0.f};
        #pragma unroll
        for (int kc = 0; kc < 4; kc++){
            const h8v af = *(const h8v*)&xT[ns * 16 + l15][kc * 32 + quad * 8];
            acc = __builtin_amdgcn_mfma_f32_16x16x32_f16(af, bw[kc], acc, 0, 0, 0);
        }
        h4v pv;
        #pragma unroll
        for (int r = 0; r < 4; r++) pv[r] = (f16)acc[r];
        *(h4v*)&rep[w][l15 * 72 + ns * 16 + quad * 4] = pv;
    }
    #pragma unroll
    for (int j = 0; j < 2; j++){
        const h8v vv = *(const h8v*)&rep[w][(rrow + 8 * j) * 72 + rcol];
        *(h8v*)&gbuf[((size_t)(b * CB + w * 16 + rrow + 8 * j)) * NN + n0 + rcol] = vv;
    }
}

// ---------------------------------------------------------------------------
// Kernel 2: fused attention + final projection + residual.
// R18 = split-K flash: 512-thread blocks, 8 waves, grid 512 (2 blocks/CU =
// 16 waves/CU = 4 waves/SIMD, 2x R17's occupancy).
//   wave w: query group wq = w&3 (16 q), key half h = w>>2
//   step m (0..63): waves h=0 compute 32-key tile 2m, h=1 tile 2m+1
//   6 tile slots (32-key: ph 4KB + g 4KB), counted vmcnt(2), raw barriers
//   (T3/T4 carried from R17), defer-max softmax, end merge per wave pair.
// LDS 58KB: PH[6][32*64] | GG[6][64*32] | PLD[8][16*40]; epilogue overlays.
// ---------------------------------------------------------------------------
__global__ __launch_bounds__(512, 4) void attn_kernel(
    const f16* __restrict__ thetaT, const f16* __restrict__ phiT,
    const f16* __restrict__ gbuf, const f16* __restrict__ wlp,
    const float* __restrict__ x, float* __restrict__ out)
{
    __shared__ __align__(16) char SM[59392];
    f16*   const PH  = (f16*)SM;                // [6][32*64]  24576 B
    f16*   const GG  = (f16*)(SM + 24576);      // [6][64*32]  24576 B
    f16*   const PLD = (f16*)(SM + 49152);      // [8][16*40]  10240 B
    // epilogue overlays (staging dead):
    float* const MG  = (float*)SM;              // [4][16][68] 17408 B
    float* const ML  = (float*)(SM + 17408);    // [4][16][2]    512 B
    float* const FO  = (float*)SM;              // [128][68]   34816 B
    f16*   const YY  = (f16*)(SM + 36864);      // [64][72]     9216 B

    const int b  = blockIdx.x & 7;              // batch -> XCD swizzle
    const int q0 = (blockIdx.x >> 3) << 6;
    const int t  = threadIdx.x;
    const int w  = t >> 6;                      // 0..7
    const int lane = t & 63, quad = lane >> 4, l15 = lane & 15;
    const int wq = w & 3;                       // query group
    const int h  = w >> 2;                      // key half (even/odd tiles)
    const int n0 = q0 + wq * 16;

    // theta fragments (16 queries per wave)
    const size_t trow = ((size_t)(b * NN + n0 + l15)) * CB;
    const h8v a0 = *(const h8v*)&thetaT[trow + quad * 8];
    const h8v a1 = *(const h8v*)&thetaT[trow + 32 + quad * 8];

    // ---- staging assignment: 16 x 1KB segments/step, 2 per wave ----
    // seg = 2w: tsel = even/odd tile, kind = ph/g, quarters qa, qa+1
    const int seg  = w * 2;
    const int tsel = seg >> 3;
    const int kind = (seg >> 2) & 1;
    const int qa   = seg & 3;                   // 0 or 2 (wave-uniform)
    const f16* sA;  const f16* sB;  size_t adv;
    if (kind == 0){                             // ph tile [key32][cb64]
        const int row = qa * 8 + (lane >> 3);
        const int gr  = (lane & 7) ^ (lane >> 3);        // XOR-swz source
        sA = phiT + ((size_t)(b * NN + tsel * 32 + row)) * CB + gr * 8;
        sB = sA + (size_t)8 * CB;
        adv = (size_t)64 * CB;                  // +2 tiles per step
    } else {                                    // g tile [cb64][key32]
        const int row = qa * 16 + (lane >> 2);
        const int gr  = (lane & 3) ^ ((lane >> 2) & 3);
        sA = gbuf + ((size_t)(b * CB + row)) * NN + tsel * 32 + gr * 8;
        sB = sA + (size_t)16 * NN;
        adv = 64;
    }
    f16* const dBase = (kind == 0) ? PH : GG;
    const int dOff = qa * 512;                  // f16 units (wave-uniform)

    // swizzled read offsets
    const int so0 = (quad ^ (l15 & 7)) * 8;     // ph: cb granule quad
    const int so1 = so0 ^ 32;                   //     cb granule quad+4
    const int go  = (quad ^ (l15 & 3)) * 8;     // g : key granule quad

    // prologue: stage tile pairs 0 (slots tsel) and 1 (slots 2+tsel)
    {
        f16* d0 = dBase + (0 + tsel) * 2048 + dOff;
        GLD(sA, d0);  GLD(sB, d0 + 512);
        f16* d1 = dBase + (2 + tsel) * 2048 + dOff;
        GLD(sA + adv, d1);  GLD(sB + adv, d1 + 512);
    }
    const f16* pA = sA + 2 * adv;
    const f16* pB = sB + 2 * adv;

    float mrun = -1e30f, lrun = 0.f;
    const f4v zf = {0.f, 0.f, 0.f, 0.f};
    f4v o[4];
    #pragma unroll
    for (int tt = 0; tt < 4; tt++) o[tt] = zf;

    f16* const PW = PLD + w * 640;              // wave-private P [16][40]

    int rc = 0;                                 // m % 3   (compute slot pair)
    int rs = 2;                                 // (m+2)%3 (stage slot pair)
    for (int m = 0; m < 64; m++){
        if (m < 63) WAITV2(); else WAITV0();    // pair m landed; never drain
        WAITL0();
        __builtin_amdgcn_s_barrier();
        asm volatile("" ::: "memory");
        if (m < 62){                            // stage pair m+2
            f16* d = dBase + (2 * rs + tsel) * 2048 + dOff;
            GLD(pA, d);  GLD(pB, d + 512);
            pA += adv;   pB += adv;
        }
        const int ct = 2 * rc + h;              // this wave's tile slot
        const f16* phc = PH + ct * 2048;
        const f16* ggc = GG + ct * 2048;

        // ---- S^T = phi(A) * theta(B), 32 keys ----
        f4v s[2];
        __builtin_amdgcn_s_setprio(1);
        #pragma unroll
        for (int tt = 0; tt < 2; tt++){
            const f16* pr = phc + (tt * 16 + l15) * 64;
            const h8v pb0 = *(const h8v*)(pr + so0);
            const h8v pb1 = *(const h8v*)(pr + so1);
            f4v sv = zf;
            sv = __builtin_amdgcn_mfma_f32_16x16x32_f16(pb0, a0, sv, 0, 0, 0);
            sv = __builtin_amdgcn_mfma_f32_16x16x32_f16(pb1, a1, sv, 0, 0, 0);
            s[tt] = sv;
        }
        __builtin_amdgcn_s_setprio(0);

        // ---- online softmax, defer-max (log2 domain; lane owns query l15) ----
        float smax = fmaxf(fmaxf(s[0][0], s[0][1]), fmaxf(s[0][2], s[0][3]));
        smax = fmaxf(smax, fmaxf(fmaxf(s[1][0], s[1][1]), fmaxf(s[1][2], s[1][3])));
        smax = fmaxf(smax, __shfl_xor(smax, 16));
        smax = fmaxf(smax, __shfl_xor(smax, 32));

        if (__any(smax - mrun > 8.f)){
            const float mn = fmaxf(mrun, smax);
            const float alpha = __builtin_amdgcn_exp2f(mrun - mn);
            mrun = mn;
            lrun *= alpha;
            #pragma unroll
            for (int tt = 0; tt < 4; tt++)
                #pragma unroll
                for (int r = 0; r < 4; r++)
                    o[tt][r] *= alpha;
        }

        float lsum = 0.f;
        #pragma unroll
        for (int tt = 0; tt < 2; tt++){
            h4v pv;
            #pragma unroll
            for (int r = 0; r < 4; r++){
                float p = __builtin_amdgcn_exp2f(s[tt][r] - mrun);
                lsum += p;
                pv[r] = (f16)p;
            }
            *(h4v*)&PW[l15 * 40 + tt * 16 + quad * 4] = pv;
        }
        lrun += lsum;

        const h8v pa = *(const h8v*)&PW[l15 * 40 + quad * 8];

        // ---- O^T += g(A) * P^T(B) ----
        __builtin_amdgcn_s_setprio(1);
        #pragma unroll
        for (int tt2 = 0; tt2 < 4; tt2++){
            const h8v gb = *(const h8v*)(ggc + (tt2 * 16 + l15) * 32 + go);
            o[tt2] = __builtin_amdgcn_mfma_f32_16x16x32_f16(gb, pa, o[tt2], 0, 0, 0);
        }
        __builtin_amdgcn_s_setprio(0);

        rc = (rc == 2) ? 0 : rc + 1;
        rs = (rs == 2) ? 0 : rs + 1;
    }

    // per-wave l reduce across quads (full l for this wave's key half)
    lrun += __shfl_xor(lrun, 16);
    lrun += __shfl_xor(lrun, 32);

    __syncthreads();   // K-loop done; staging region dead -> merge overlay

    if (h == 1){       // odd-half waves publish (m, l, O)
        #pragma unroll
        for (int tt2 = 0; tt2 < 4; tt2++)
            *(f4v*)&MG[wq * 1088 + l15 * 68 + tt2 * 16 + quad * 4] = o[tt2];
        if (lane < 16){
            ML[wq * 32 + lane * 2 + 0] = mrun;
            ML[wq * 32 + lane * 2 + 1] = lrun;
        }
    }
    __syncthreads();

    if (h == 0){       // even-half waves merge + normalize -> y (f16)
        const float m4 = ML[wq * 32 + l15 * 2 + 0];
        const float l4 = ML[wq * 32 + l15 * 2 + 1];
        const float M  = fmaxf(mrun, m4);
        const float e0 = __builtin_amdgcn_exp2f(mrun - M);
        const float e1 = __builtin_amdgcn_exp2f(m4 - M);
        const float inv = 1.0f / (lrun * e0 + l4 * e1);
        #pragma unroll
        for (int tt2 = 0; tt2 < 4; tt2++){
            const f4v o4 = *(const f4v*)&MG[wq * 1088 + l15 * 68 + tt2 * 16 + quad * 4];
            h4v yv;
            #pragma unroll
            for (int r = 0; r < 4; r++)
                yv[r] = (f16)((o[tt2][r] * e0 + o4[r] * e1) * inv);
            *(h4v*)&YY[(wq * 16 + l15) * 72 + tt2 * 16 + quad * 4] = yv;
        }
    }
    __syncthreads();

    // ---- out-GEMM: D[c][q] = wl(A) * y(B); 8 waves, 4 cs each ----
    const h8v yB0 = *(const h8v*)&YY[(wq * 16 + l15) * 72 + quad * 8];
    const h8v yB1 = *(const h8v*)&YY[(wq * 16 + l15) * 72 + 32 + quad * 8];
    #pragma unroll
    for (int ci = 0; ci < 4; ci++){
        const int cs = h * 4 + ci;
        const h8v wa0 = *(const h8v*)&wlp[(cs * 2 + 0) * 512 + lane * 8];
        const h8v wa1 = *(const h8v*)&wlp[(cs * 2 + 1) * 512 + lane * 8];
        f4v acc = zf;
        acc = __builtin_amdgcn_mfma_f32_16x16x32_f16(wa0, yB0, acc, 0, 0, 0);
        acc = __builtin_amdgcn_mfma_f32_16x16x32_f16(wa1, yB1, acc, 0, 0, 0);
        #pragma unroll
        for (int r = 0; r < 4; r++)
            FO[(cs * 16 + quad * 4 + r) * 68 + wq * 16 + l15] = acc[r];
    }
    __syncthreads();

    // ---- residual RMW: fully coalesced float4, 512 threads ----
    #pragma unroll
    for (int i = 0; i < 4; i++){
        const int row = i * 32 + (t >> 4);
        const int nf  = (t & 15) * 4;
        const f4v v = *(const f4v*)&FO[row * 68 + nf];
        const size_t idx = ((size_t)(b * CC + row)) * NN + q0 + nf;
        const f4v xv = *(const f4v*)&x[idx];
        f4v ov;
        #pragma unroll
        for (int r = 0; r < 4; r++) ov[r] = v[r] + xv[r];
        *(f4v*)&out[idx] = ov;
    }
}

extern "C" void kernel_launch(void* const* d_in, const int* in_sizes, int n_in,
                              void* d_out, int out_size, void* d_ws, size_t ws_size,
                              hipStream_t stream)
{
    const float* x   = (const float*)d_in[0];
    const float* wth = (const float*)d_in[1];
    const float* wph = (const float*)d_in[2];
    const float* wg  = (const float*)d_in[3];
    const float* wl  = (const float*)d_in[4];
    float* out = (float*)d_out;

    f16* thetaT = (f16*)d_ws;
    f16* phiT   = thetaT + (size_t)NB * NN * CB;
    f16* gbuf   = phiT   + (size_t)NB * NN * CB;
    f16* wthp   = gbuf   + (size_t)NB * NN * CB;
    f16* wphp   = wthp + 8192;
    f16* wgp    = wphp + 8192;
    f16* wlp    = wgp  + 8192;

    pack_w<<<8, 256, 0, stream>>>(wth, wph, wg, wl, wthp, wphp, wgp, wlp);
    proj_kernel<<<NB * 64, 256, 0, stream>>>(x, wthp, wphp, wgp, thetaT, phiT, gbuf);
    attn_kernel<<<NB * 64, 512, 0, stream>>>(thetaT, phiT, gbuf, wlp, x, out);
}